// Round 1
// baseline (149.782 us; speedup 1.0000x reference)
//
#include <hip/hip_runtime.h>
#include <math.h>

#define NT 4096
#define EMB 1024
#define DH 64
#define PLANE (NT * DH)          // 262144 floats = 1 MB
#define NSPLIT 4
#define KPS (NT / NSPLIT)        // 1024 keys per split

// ---------------------------------------------------------------------------
// Kernel 1: fused QKV projection.  qkv = [Q | K | V] planes, each (NT, DH).
// 256 blocks x 256 threads; block owns 16 token rows x all 192 output cols.
// ---------------------------------------------------------------------------
__global__ __launch_bounds__(256) void proj_kernel(
    const float* __restrict__ tokens, const float* __restrict__ wq,
    const float* __restrict__ wk, const float* __restrict__ wv,
    float* __restrict__ qkv)
{
    __shared__ float tok_t[64][16];     // [k][row], 4 KB
    __shared__ float w_tile[64][192];   // [k][col(Q|K|V)], 48 KB

    const int t = threadIdx.x;
    const int rowbase = blockIdx.x * 16;
    const int r0 = (t >> 5) * 2;        // 2 rows per thread
    const int c0 = (t & 31) * 6;        // 6 cols per thread

    float acc[2][6];
#pragma unroll
    for (int i = 0; i < 2; ++i)
#pragma unroll
        for (int j = 0; j < 6; ++j) acc[i][j] = 0.f;

    const int srow = t & 15;            // staging: local token row
    const int sc4  = t >> 4;            // staging: k-quarter (0..15)

    for (int kb = 0; kb < EMB / 64; ++kb) {
        __syncthreads();
        // stage tokens tile (transposed): 16 rows x 64 k
        {
            float4 v = *(const float4*)&tokens[(rowbase + srow) * EMB + kb * 64 + sc4 * 4];
            tok_t[sc4 * 4 + 0][srow] = v.x;
            tok_t[sc4 * 4 + 1][srow] = v.y;
            tok_t[sc4 * 4 + 2][srow] = v.z;
            tok_t[sc4 * 4 + 3][srow] = v.w;
        }
        // stage weight tile: 64 k x (64 Q + 64 K + 64 V)
#pragma unroll
        for (int i = 0; i < 4; ++i) {
            int flat = i * 256 + t;                 // 0..1023
            int wr = flat >> 4;                     // 0..63
            int cc = (flat & 15) * 4;               // 0..60
            int gidx = (kb * 64 + wr) * DH + cc;
            *(float4*)&w_tile[wr][cc]        = *(const float4*)&wq[gidx];
            *(float4*)&w_tile[wr][64 + cc]   = *(const float4*)&wk[gidx];
            *(float4*)&w_tile[wr][128 + cc]  = *(const float4*)&wv[gidx];
        }
        __syncthreads();
#pragma unroll 8
        for (int kk = 0; kk < 64; ++kk) {
            float2 a  = *(const float2*)&tok_t[kk][r0];
            float2 b0 = *(const float2*)&w_tile[kk][c0];
            float2 b1 = *(const float2*)&w_tile[kk][c0 + 2];
            float2 b2 = *(const float2*)&w_tile[kk][c0 + 4];
            acc[0][0] += a.x * b0.x; acc[0][1] += a.x * b0.y;
            acc[0][2] += a.x * b1.x; acc[0][3] += a.x * b1.y;
            acc[0][4] += a.x * b2.x; acc[0][5] += a.x * b2.y;
            acc[1][0] += a.y * b0.x; acc[1][1] += a.y * b0.y;
            acc[1][2] += a.y * b1.x; acc[1][3] += a.y * b1.y;
            acc[1][4] += a.y * b2.x; acc[1][5] += a.y * b2.y;
        }
    }
#pragma unroll
    for (int rr = 0; rr < 2; ++rr)
#pragma unroll
        for (int cc = 0; cc < 6; ++cc) {
            int col = c0 + cc;
            qkv[(col >> 6) * PLANE + (rowbase + r0 + rr) * DH + (col & 63)] = acc[rr][cc];
        }
}

// ---------------------------------------------------------------------------
// Kernel 2: flash attention with K-split.  grid (64 q-blocks, NSPLIT).
// Block: 256 thr, QBLK=64, KBLK=64.  Thread (tr,tc) owns 4 q-rows x 4 j-cols
// for S, and 4 q-rows x 4 d-cols for O.  Writes partial O + (m,l) per row.
// ---------------------------------------------------------------------------
__global__ __launch_bounds__(256) void attn_kernel(
    const float* __restrict__ qkv, const float* __restrict__ mask,
    float* __restrict__ opart, float* __restrict__ mlbuf)
{
    __shared__ float Qt[64][64];   // [d][row] 16 KB
    __shared__ float Kt[64][64];   // [d][j]   16 KB
    __shared__ float Vs[64][64];   // [j][d]   16 KB
    __shared__ float Pt[64][68];   // [j][row] padded, ~17 KB

    const float* Q  = qkv;
    const float* Kp = qkv + PLANE;
    const float* Vp = qkv + 2 * PLANE;

    const int t  = threadIdx.x;
    const int qb = blockIdx.x;
    const int sp = blockIdx.y;
    const int tr = t >> 4, tc = t & 15;
    const int r0 = tr * 4, j0 = tc * 4;
    const int srow = t & 63;       // staging row
    const int sq   = t >> 6;       // staging col quarter (0..3)

    // stage Q transposed (once per block)
#pragma unroll
    for (int i = 0; i < 4; ++i) {
        int col = sq * 16 + i * 4;
        float4 v = *(const float4*)&Q[(qb * 64 + srow) * DH + col];
        Qt[col + 0][srow] = v.x;
        Qt[col + 1][srow] = v.y;
        Qt[col + 2][srow] = v.z;
        Qt[col + 3][srow] = v.w;
    }

    float o[4][4], m[4], l[4];
#pragma unroll
    for (int r = 0; r < 4; ++r) {
        m[r] = -INFINITY; l[r] = 0.f;
#pragma unroll
        for (int c = 0; c < 4; ++c) o[r][c] = 0.f;
    }

    for (int cb = 0; cb < KPS / 64; ++cb) {
        const int kv = sp * KPS + cb * 64;
        __syncthreads();   // previous iter's PV reads done before re-staging
        // stage K transposed
#pragma unroll
        for (int i = 0; i < 4; ++i) {
            int col = sq * 16 + i * 4;
            float4 v = *(const float4*)&Kp[(kv + srow) * DH + col];
            Kt[col + 0][srow] = v.x;
            Kt[col + 1][srow] = v.y;
            Kt[col + 2][srow] = v.z;
            Kt[col + 3][srow] = v.w;
        }
        // stage V straight
        {
            int vrow = t >> 2;
            int vc = (t & 3) * 16;
#pragma unroll
            for (int i = 0; i < 4; ++i) {
                *(float4*)&Vs[vrow][vc + i * 4] =
                    *(const float4*)&Vp[(kv + vrow) * DH + vc + i * 4];
            }
        }
        __syncthreads();

        // ---- S = Q K^T, 4x4 micro-tile ----
        float s[4][4];
#pragma unroll
        for (int r = 0; r < 4; ++r)
#pragma unroll
            for (int c = 0; c < 4; ++c) s[r][c] = 0.f;

#pragma unroll 8
        for (int d = 0; d < 64; ++d) {
            float4 a = *(const float4*)&Qt[d][r0];
            float4 b = *(const float4*)&Kt[d][j0];
            s[0][0] += a.x * b.x; s[0][1] += a.x * b.y; s[0][2] += a.x * b.z; s[0][3] += a.x * b.w;
            s[1][0] += a.y * b.x; s[1][1] += a.y * b.y; s[1][2] += a.y * b.z; s[1][3] += a.y * b.w;
            s[2][0] += a.z * b.x; s[2][1] += a.z * b.y; s[2][2] += a.z * b.z; s[2][3] += a.z * b.w;
            s[3][0] += a.w * b.x; s[3][1] += a.w * b.y; s[3][2] += a.w * b.z; s[3][3] += a.w * b.w;
        }

        // multiplicative mask, then 1/sqrt(64)
        float4 mk = *(const float4*)&mask[kv + j0];
#pragma unroll
        for (int r = 0; r < 4; ++r) {
            s[r][0] *= mk.x * 0.125f;
            s[r][1] *= mk.y * 0.125f;
            s[r][2] *= mk.z * 0.125f;
            s[r][3] *= mk.w * 0.125f;
        }

        // ---- online softmax (row groups = 16 lanes sharing tr) ----
        float fr[4];
#pragma unroll
        for (int r = 0; r < 4; ++r) {
            float rmax = fmaxf(fmaxf(s[r][0], s[r][1]), fmaxf(s[r][2], s[r][3]));
#pragma unroll
            for (int off = 1; off < 16; off <<= 1)
                rmax = fmaxf(rmax, __shfl_xor(rmax, off));
            float mn = fmaxf(m[r], rmax);
            fr[r] = __expf(m[r] - mn);
            s[r][0] = __expf(s[r][0] - mn);
            s[r][1] = __expf(s[r][1] - mn);
            s[r][2] = __expf(s[r][2] - mn);
            s[r][3] = __expf(s[r][3] - mn);
            float rs = s[r][0] + s[r][1] + s[r][2] + s[r][3];
#pragma unroll
            for (int off = 1; off < 16; off <<= 1)
                rs += __shfl_xor(rs, off);
            l[r] = l[r] * fr[r] + rs;
            m[r] = mn;
        }

        // write P transposed: Pt[j][row]
#pragma unroll
        for (int jl = 0; jl < 4; ++jl) {
            *(float4*)&Pt[j0 + jl][r0] =
                make_float4(s[0][jl], s[1][jl], s[2][jl], s[3][jl]);
        }
        __syncthreads();

        // ---- O = O*f + P V ----
#pragma unroll
        for (int r = 0; r < 4; ++r)
#pragma unroll
            for (int c = 0; c < 4; ++c) o[r][c] *= fr[r];

#pragma unroll 8
        for (int j = 0; j < 64; ++j) {
            float4 p = *(const float4*)&Pt[j][r0];   // rows r0..r0+3
            float4 v = *(const float4*)&Vs[j][j0];   // d-cols j0..j0+3
            o[0][0] += p.x * v.x; o[0][1] += p.x * v.y; o[0][2] += p.x * v.z; o[0][3] += p.x * v.w;
            o[1][0] += p.y * v.x; o[1][1] += p.y * v.y; o[1][2] += p.y * v.z; o[1][3] += p.y * v.w;
            o[2][0] += p.z * v.x; o[2][1] += p.z * v.y; o[2][2] += p.z * v.z; o[2][3] += p.z * v.w;
            o[3][0] += p.w * v.x; o[3][1] += p.w * v.y; o[3][2] += p.w * v.z; o[3][3] += p.w * v.w;
        }
    }

    // write partials (un-normalized O plus m,l)
#pragma unroll
    for (int rr = 0; rr < 4; ++rr) {
        int row = qb * 64 + r0 + rr;
        *(float4*)&opart[(size_t)(sp * NT + row) * DH + j0] =
            make_float4(o[rr][0], o[rr][1], o[rr][2], o[rr][3]);
        if (tc == 0) {
            mlbuf[(sp * NT + row) * 2 + 0] = m[rr];
            mlbuf[(sp * NT + row) * 2 + 1] = l[rr];
        }
    }
}

// ---------------------------------------------------------------------------
// Kernel 3: merge NSPLIT partials -> final output.
// ---------------------------------------------------------------------------
__global__ __launch_bounds__(256) void merge_kernel(
    const float* __restrict__ opart, const float* __restrict__ mlbuf,
    float* __restrict__ out)
{
    int idx = (blockIdx.x * 256 + threadIdx.x) * 4;   // flat float index
    int row = idx >> 6;
    int d0  = idx & 63;

    float mv[NSPLIT], lv[NSPLIT];
    float mstar = -INFINITY;
#pragma unroll
    for (int s = 0; s < NSPLIT; ++s) {
        mv[s] = mlbuf[(s * NT + row) * 2 + 0];
        lv[s] = mlbuf[(s * NT + row) * 2 + 1];
        mstar = fmaxf(mstar, mv[s]);
    }
    float denom = 0.f;
    float ax = 0.f, ay = 0.f, az = 0.f, aw = 0.f;
#pragma unroll
    for (int s = 0; s < NSPLIT; ++s) {
        float w = __expf(mv[s] - mstar);
        denom += w * lv[s];
        float4 ov = *(const float4*)&opart[(size_t)(s * NT + row) * DH + d0];
        ax += w * ov.x; ay += w * ov.y; az += w * ov.z; aw += w * ov.w;
    }
    float inv = 1.f / denom;
    *(float4*)&out[idx] = make_float4(ax * inv, ay * inv, az * inv, aw * inv);
}

// ---------------------------------------------------------------------------
extern "C" void kernel_launch(void* const* d_in, const int* in_sizes, int n_in,
                              void* d_out, int out_size, void* d_ws, size_t ws_size,
                              hipStream_t stream) {
    const float* tokens = (const float*)d_in[0];
    const float* mask   = (const float*)d_in[1];
    const float* wq     = (const float*)d_in[2];
    const float* wk     = (const float*)d_in[3];
    const float* wv     = (const float*)d_in[4];

    float* ws    = (float*)d_ws;
    float* qkv   = ws;                            // 3 planes
    float* opart = ws + 3 * PLANE;                // NSPLIT planes
    float* mlbuf = ws + (3 + NSPLIT) * PLANE;     // NSPLIT*NT*2 floats
    float* out   = (float*)d_out;

    hipLaunchKernelGGL(proj_kernel, dim3(NT / 16), dim3(256), 0, stream,
                       tokens, wq, wk, wv, qkv);
    hipLaunchKernelGGL(attn_kernel, dim3(NT / 64, NSPLIT), dim3(256), 0, stream,
                       qkv, mask, opart, mlbuf);
    hipLaunchKernelGGL(merge_kernel, dim3(256), dim3(256), 0, stream,
                       opart, mlbuf, out);
}

// Round 2
// 82.243 us; speedup vs baseline: 1.8212x; 1.8212x over previous
//
#include <hip/hip_runtime.h>
#include <math.h>

#define NT 4096
#define EMB 1024
#define DH 64
#define PLANE (NT * DH)          // 262144
#define NSPLIT 8
#define KPS (NT / NSPLIT)        // 512
#define KVB 64

typedef __attribute__((ext_vector_type(8))) short short8;
typedef __attribute__((ext_vector_type(16))) float f32x16;

union U8 { short8 s; uint4 u; unsigned short h[8]; unsigned int w[4]; };

static __device__ __forceinline__ unsigned short f2bf(float x) {
    union { float f; unsigned int u; } v; v.f = x;
    unsigned int r = v.u + 0x7fffu + ((v.u >> 16) & 1u);
    return (unsigned short)(r >> 16);
}
static __device__ __forceinline__ float bf2f(unsigned short h) {
    union { unsigned int u; float f; } v; v.u = ((unsigned int)h) << 16;
    return v.f;
}
static __device__ __forceinline__ unsigned int pk2(float a, float b) {
    return (unsigned int)f2bf(a) | ((unsigned int)f2bf(b) << 16);
}

// ---------------------------------------------------------------------------
// Kernel 1: fused QKV projection (fp32, unchanged from R1; MFMA next round).
// ---------------------------------------------------------------------------
__global__ __launch_bounds__(256) void proj_kernel(
    const float* __restrict__ tokens, const float* __restrict__ wq,
    const float* __restrict__ wk, const float* __restrict__ wv,
    float* __restrict__ qkv)
{
    __shared__ float tok_t[64][16];
    __shared__ float w_tile[64][192];

    const int t = threadIdx.x;
    const int rowbase = blockIdx.x * 16;
    const int r0 = (t >> 5) * 2;
    const int c0 = (t & 31) * 6;

    float acc[2][6];
#pragma unroll
    for (int i = 0; i < 2; ++i)
#pragma unroll
        for (int j = 0; j < 6; ++j) acc[i][j] = 0.f;

    const int srow = t & 15;
    const int sc4  = t >> 4;

    for (int kb = 0; kb < EMB / 64; ++kb) {
        __syncthreads();
        {
            float4 v = *(const float4*)&tokens[(rowbase + srow) * EMB + kb * 64 + sc4 * 4];
            tok_t[sc4 * 4 + 0][srow] = v.x;
            tok_t[sc4 * 4 + 1][srow] = v.y;
            tok_t[sc4 * 4 + 2][srow] = v.z;
            tok_t[sc4 * 4 + 3][srow] = v.w;
        }
#pragma unroll
        for (int i = 0; i < 4; ++i) {
            int flat = i * 256 + t;
            int wr = flat >> 4;
            int cc = (flat & 15) * 4;
            int gidx = (kb * 64 + wr) * DH + cc;
            *(float4*)&w_tile[wr][cc]        = *(const float4*)&wq[gidx];
            *(float4*)&w_tile[wr][64 + cc]   = *(const float4*)&wk[gidx];
            *(float4*)&w_tile[wr][128 + cc]  = *(const float4*)&wv[gidx];
        }
        __syncthreads();
#pragma unroll 8
        for (int kk = 0; kk < 64; ++kk) {
            float2 a  = *(const float2*)&tok_t[kk][r0];
            float2 b0 = *(const float2*)&w_tile[kk][c0];
            float2 b1 = *(const float2*)&w_tile[kk][c0 + 2];
            float2 b2 = *(const float2*)&w_tile[kk][c0 + 4];
            acc[0][0] += a.x * b0.x; acc[0][1] += a.x * b0.y;
            acc[0][2] += a.x * b1.x; acc[0][3] += a.x * b1.y;
            acc[0][4] += a.x * b2.x; acc[0][5] += a.x * b2.y;
            acc[1][0] += a.y * b0.x; acc[1][1] += a.y * b0.y;
            acc[1][2] += a.y * b1.x; acc[1][3] += a.y * b1.y;
            acc[1][4] += a.y * b2.x; acc[1][5] += a.y * b2.y;
        }
    }
#pragma unroll
    for (int rr = 0; rr < 2; ++rr)
#pragma unroll
        for (int cc = 0; cc < 6; ++cc) {
            int col = c0 + cc;
            qkv[(col >> 6) * PLANE + (rowbase + r0 + rr) * DH + (col & 63)] = acc[rr][cc];
        }
}

// ---------------------------------------------------------------------------
// Kernel 2: convert K -> split-bf16 (mask*0.125 folded in), V -> bf16.
// ---------------------------------------------------------------------------
__global__ __launch_bounds__(256) void conv_kernel(
    const float* __restrict__ qkv, const float* __restrict__ mask,
    unsigned short* __restrict__ Khg, unsigned short* __restrict__ Klg,
    unsigned short* __restrict__ Vbg)
{
    int tid  = blockIdx.x * 256 + threadIdx.x;   // 65536 total
    int half = tid >> 15;
    int r    = (tid & 32767) >> 3;
    int dg   = tid & 7;
    if (half == 0) {
        const float* Kp = qkv + PLANE;
        float4 a = *(const float4*)&Kp[r * DH + dg * 8];
        float4 b = *(const float4*)&Kp[r * DH + dg * 8 + 4];
        float mk = mask[r] * 0.125f;
        float x[8] = {a.x, a.y, a.z, a.w, b.x, b.y, b.z, b.w};
        U8 H, L;
#pragma unroll
        for (int i = 0; i < 8; ++i) {
            float s = x[i] * mk;
            H.h[i] = f2bf(s);
            L.h[i] = f2bf(s - bf2f(H.h[i]));
        }
        *(uint4*)&Khg[r * DH + dg * 8] = H.u;
        *(uint4*)&Klg[r * DH + dg * 8] = L.u;
    } else {
        const float* Vp = qkv + 2 * PLANE;
        float4 a = *(const float4*)&Vp[r * DH + dg * 8];
        float4 b = *(const float4*)&Vp[r * DH + dg * 8 + 4];
        float x[8] = {a.x, a.y, a.z, a.w, b.x, b.y, b.z, b.w};
        U8 H;
#pragma unroll
        for (int i = 0; i < 8; ++i) H.h[i] = f2bf(x[i]);
        *(uint4*)&Vbg[r * DH + dg * 8] = H.u;
    }
}

// ---------------------------------------------------------------------------
// Kernel 3: MFMA flash attention, split-bf16 logits.
// Block: 4 waves x 32 q-rows = 128 q. Grid (32, NSPLIT).
// S^T = mfma(K, Q): lane holds q = lane&31, j per reg = (r&3)+8*(r>>2)+4*g.
// ---------------------------------------------------------------------------
__global__ __launch_bounds__(256) void attn_mfma(
    const float* __restrict__ qkv,
    const unsigned short* __restrict__ Khg, const unsigned short* __restrict__ Klg,
    const unsigned short* __restrict__ Vbg,
    float* __restrict__ opart, float* __restrict__ mlbuf)
{
    __shared__ unsigned short Kh[64][64];   // cols swizzled: col ^ ((j&7)*8)
    __shared__ unsigned short Kl[64][64];
    __shared__ unsigned int   V2[32][64];   // pair-packed rows, cols ^ ((j2&7)*8)

    const int t    = threadIdx.x;
    const int qb   = blockIdx.x;
    const int sp   = blockIdx.y;
    const int wq   = t >> 6;
    const int lane = t & 63;
    const int g    = lane >> 5;
    const int c    = lane & 31;
    const int qrow = qb * 128 + wq * 32 + c;

    // ---- Q fragments (hi/lo) in registers, once per block ----
    short8 qh[4], ql[4];
#pragma unroll
    for (int kt = 0; kt < 4; ++kt) {
        const float* qp = qkv + (size_t)qrow * DH + kt * 16 + g * 8;
        float4 a = *(const float4*)qp;
        float4 b = *(const float4*)(qp + 4);
        float x[8] = {a.x, a.y, a.z, a.w, b.x, b.y, b.z, b.w};
        U8 H, L;
#pragma unroll
        for (int i = 0; i < 8; ++i) {
            H.h[i] = f2bf(x[i]);
            L.h[i] = f2bf(x[i] - bf2f(H.h[i]));
        }
        qh[kt] = H.s;
        ql[kt] = L.s;
    }

    f32x16 oa[2];
#pragma unroll
    for (int i = 0; i < 16; ++i) { oa[0][i] = 0.f; oa[1][i] = 0.f; }
    float m = -INFINITY, l = 0.f;

    for (int cb = 0; cb < KPS / KVB; ++cb) {
        const int kv = sp * KPS + cb * KVB;
        __syncthreads();
        // ---- stage K hi/lo, swizzled ----
#pragma unroll
        for (int it = 0; it < 2; ++it) {
            int idx = it * 256 + t;
            int j = idx >> 3, gr = idx & 7;
            int colp = (gr * 8) ^ ((j & 7) * 8);
            *(uint4*)&Kh[j][colp] = *(const uint4*)&Khg[(size_t)(kv + j) * DH + gr * 8];
            *(uint4*)&Kl[j][colp] = *(const uint4*)&Klg[(size_t)(kv + j) * DH + gr * 8];
        }
        // ---- stage V pair-packed ----
        {
            int a2 = t >> 3, dg = t & 7;   // 32 pair-rows x 8 dgroups
            uint4 r0 = *(const uint4*)&Vbg[(size_t)(kv + a2 * 2) * DH + dg * 8];
            uint4 r1 = *(const uint4*)&Vbg[(size_t)(kv + a2 * 2 + 1) * DH + dg * 8];
            const unsigned int* p0 = (const unsigned int*)&r0;
            const unsigned int* p1 = (const unsigned int*)&r1;
            unsigned int w[8];
#pragma unroll
            for (int i = 0; i < 4; ++i) {
                w[2 * i]     = (p0[i] & 0xFFFFu) | (p1[i] << 16);
                w[2 * i + 1] = (p0[i] >> 16)     | (p1[i] & 0xFFFF0000u);
            }
            int colp = (dg * 8) ^ ((a2 & 7) * 8);
            *(uint4*)&V2[a2][colp]     = *(uint4*)&w[0];
            *(uint4*)&V2[a2][colp + 4] = *(uint4*)&w[4];
        }
        __syncthreads();

        // ---- QK^T: S^T tiles (j-tiles 0,1), 3 split passes, k = DH in 4 steps ----
        f32x16 st0, st1;
#pragma unroll
        for (int i = 0; i < 16; ++i) { st0[i] = 0.f; st1[i] = 0.f; }
#pragma unroll
        for (int kt = 0; kt < 4; ++kt) {
            int colp = ((kt * 2 + g) * 8) ^ ((c & 7) * 8);   // (row&7) == (c&7) for both tiles
            short8 kh0 = *(const short8*)&Kh[c][colp];
            short8 kl0 = *(const short8*)&Kl[c][colp];
            short8 kh1 = *(const short8*)&Kh[32 + c][colp];
            short8 kl1 = *(const short8*)&Kl[32 + c][colp];
            st0 = __builtin_amdgcn_mfma_f32_32x32x16_bf16(kh0, qh[kt], st0, 0, 0, 0);
            st1 = __builtin_amdgcn_mfma_f32_32x32x16_bf16(kh1, qh[kt], st1, 0, 0, 0);
            st0 = __builtin_amdgcn_mfma_f32_32x32x16_bf16(kh0, ql[kt], st0, 0, 0, 0);
            st1 = __builtin_amdgcn_mfma_f32_32x32x16_bf16(kh1, ql[kt], st1, 0, 0, 0);
            st0 = __builtin_amdgcn_mfma_f32_32x32x16_bf16(kl0, qh[kt], st0, 0, 0, 0);
            st1 = __builtin_amdgcn_mfma_f32_32x32x16_bf16(kl1, qh[kt], st1, 0, 0, 0);
        }

        // ---- online softmax (lane-local; combine halves via shfl_xor 32) ----
        float p[32];
        float pm = -INFINITY;
#pragma unroll
        for (int r = 0; r < 16; ++r) {
            pm = fmaxf(pm, st0[r]);
            pm = fmaxf(pm, st1[r]);
        }
        pm = fmaxf(pm, __shfl_xor(pm, 32));
        float mn = fmaxf(m, pm);
        float f  = __expf(m - mn);
        float rs = 0.f;
#pragma unroll
        for (int r = 0; r < 16; ++r) { p[r]      = __expf(st0[r] - mn); rs += p[r]; }
#pragma unroll
        for (int r = 0; r < 16; ++r) { p[16 + r] = __expf(st1[r] - mn); rs += p[16 + r]; }
        rs += __shfl_xor(rs, 32);
        l = l * f + rs;
        m = mn;

        // ---- build PA fragments in-register ----
        short8 pa[4];
#pragma unroll
        for (int jt = 0; jt < 2; ++jt) {
            const float* pp = &p[jt * 16];
            unsigned int A1 = pk2(pp[0], pp[1]),   B1 = pk2(pp[4], pp[5]);
            unsigned int A2 = pk2(pp[2], pp[3]),   B2 = pk2(pp[6], pp[7]);
            unsigned int A3 = pk2(pp[8], pp[9]),   B3 = pk2(pp[12], pp[13]);
            unsigned int A4 = pk2(pp[10], pp[11]), B4 = pk2(pp[14], pp[15]);
            unsigned int xA1 = (unsigned int)__shfl_xor((int)A1, 32);
            unsigned int xB1 = (unsigned int)__shfl_xor((int)B1, 32);
            unsigned int xA2 = (unsigned int)__shfl_xor((int)A2, 32);
            unsigned int xB2 = (unsigned int)__shfl_xor((int)B2, 32);
            unsigned int xA3 = (unsigned int)__shfl_xor((int)A3, 32);
            unsigned int xB3 = (unsigned int)__shfl_xor((int)B3, 32);
            unsigned int xA4 = (unsigned int)__shfl_xor((int)A4, 32);
            unsigned int xB4 = (unsigned int)__shfl_xor((int)B4, 32);
            U8 f0, f1;
            f0.w[0] = g ? xB1 : A1;
            f0.w[1] = g ? xB2 : A2;
            f0.w[2] = g ? B1  : xA1;
            f0.w[3] = g ? B2  : xA2;
            f1.w[0] = g ? xB3 : A3;
            f1.w[1] = g ? xB4 : A4;
            f1.w[2] = g ? B3  : xA3;
            f1.w[3] = g ? B4  : xA4;
            pa[jt * 2]     = f0.s;
            pa[jt * 2 + 1] = f1.s;
        }

        // ---- rescale O by f (per output q-row, fetched via shfl) ----
#pragma unroll
        for (int r = 0; r < 16; ++r) {
            float fr = __shfl(f, (r & 3) + 8 * (r >> 2) + 4 * g);
            oa[0][r] *= fr;
            oa[1][r] *= fr;
        }

        // ---- PV ----
#pragma unroll
        for (int dt = 0; dt < 2; ++dt) {
#pragma unroll
            for (int ks = 0; ks < 4; ++ks) {
                U8 bf;
#pragma unroll
                for (int pq = 0; pq < 4; ++pq) {
                    int j2 = ks * 8 + g * 4 + pq;
                    int col = (dt * 32 + c) ^ ((j2 & 7) * 8);
                    bf.w[pq] = V2[j2][col];
                }
                oa[dt] = __builtin_amdgcn_mfma_f32_32x32x16_bf16(pa[ks], bf.s, oa[dt], 0, 0, 0);
            }
        }
    }

    // ---- epilogue: un-normalized partial O + (m,l) ----
#pragma unroll
    for (int dt = 0; dt < 2; ++dt)
#pragma unroll
        for (int r = 0; r < 16; ++r) {
            int row = qb * 128 + wq * 32 + ((r & 3) + 8 * (r >> 2) + 4 * g);
            opart[((size_t)sp * NT + row) * DH + dt * 32 + c] = oa[dt][r];
        }
    if (lane < 32) {
        int row = qb * 128 + wq * 32 + lane;
        mlbuf[((size_t)sp * NT + row) * 2 + 0] = m;
        mlbuf[((size_t)sp * NT + row) * 2 + 1] = l;
    }
}

// ---------------------------------------------------------------------------
// Kernel 4: merge NSPLIT partials -> final output.
// ---------------------------------------------------------------------------
__global__ __launch_bounds__(256) void merge_kernel(
    const float* __restrict__ opart, const float* __restrict__ mlbuf,
    float* __restrict__ out)
{
    int idx = (blockIdx.x * 256 + threadIdx.x) * 4;
    int row = idx >> 6;
    int d0  = idx & 63;

    float mv[NSPLIT], lv[NSPLIT];
    float mstar = -INFINITY;
#pragma unroll
    for (int s = 0; s < NSPLIT; ++s) {
        mv[s] = mlbuf[((size_t)s * NT + row) * 2 + 0];
        lv[s] = mlbuf[((size_t)s * NT + row) * 2 + 1];
        mstar = fmaxf(mstar, mv[s]);
    }
    float denom = 0.f;
    float ax = 0.f, ay = 0.f, az = 0.f, aw = 0.f;
#pragma unroll
    for (int s = 0; s < NSPLIT; ++s) {
        float w = __expf(mv[s] - mstar);
        denom += w * lv[s];
        float4 ov = *(const float4*)&opart[((size_t)s * NT + row) * DH + d0];
        ax += w * ov.x; ay += w * ov.y; az += w * ov.z; aw += w * ov.w;
    }
    float inv = 1.f / denom;
    *(float4*)&out[idx] = make_float4(ax * inv, ay * inv, az * inv, aw * inv);
}

// ---------------------------------------------------------------------------
extern "C" void kernel_launch(void* const* d_in, const int* in_sizes, int n_in,
                              void* d_out, int out_size, void* d_ws, size_t ws_size,
                              hipStream_t stream) {
    const float* tokens = (const float*)d_in[0];
    const float* mask   = (const float*)d_in[1];
    const float* wq     = (const float*)d_in[2];
    const float* wk     = (const float*)d_in[3];
    const float* wv     = (const float*)d_in[4];

    float* ws    = (float*)d_ws;
    float* qkv   = ws;                                   // 3*PLANE floats
    unsigned short* Khg = (unsigned short*)(ws + 3 * PLANE);
    unsigned short* Klg = Khg + PLANE;
    unsigned short* Vbg = Klg + PLANE;
    float* opart = ws + 3 * PLANE + (3 * PLANE) / 2;     // NSPLIT*PLANE floats
    float* mlbuf = opart + (size_t)NSPLIT * PLANE;       // NSPLIT*NT*2 floats
    float* out   = (float*)d_out;

    hipLaunchKernelGGL(proj_kernel, dim3(NT / 16), dim3(256), 0, stream,
                       tokens, wq, wk, wv, qkv);
    hipLaunchKernelGGL(conv_kernel, dim3(256), dim3(256), 0, stream,
                       qkv, mask, Khg, Klg, Vbg);
    hipLaunchKernelGGL(attn_mfma, dim3(NT / 128, NSPLIT), dim3(256), 0, stream,
                       qkv, Khg, Klg, Vbg, opart, mlbuf);
    hipLaunchKernelGGL(merge_kernel, dim3(256), dim3(256), 0, stream,
                       opart, mlbuf, out);
}

// Round 3
// 56.149 us; speedup vs baseline: 2.6676x; 1.4647x over previous
//
#include <hip/hip_runtime.h>
#include <math.h>

#define NT 4096
#define EMB 1024
#define DH 64
#define PLANE (NT * DH)          // 262144
#define NSPLIT 8                 // attention K-split
#define KPS (NT / NSPLIT)        // 512
#define KVB 64
#define KSPLIT 4                 // projection K-split (EMB/4 = 256 per block)

typedef __attribute__((ext_vector_type(8))) short short8;
typedef __attribute__((ext_vector_type(16))) float f32x16;
typedef unsigned short u16;

union U8 { short8 s; uint4 u; unsigned short h[8]; unsigned int w[4]; };

static __device__ __forceinline__ unsigned short f2bf(float x) {
    union { float f; unsigned int u; } v; v.f = x;
    unsigned int r = v.u + 0x7fffu + ((v.u >> 16) & 1u);
    return (unsigned short)(r >> 16);
}
static __device__ __forceinline__ float bf2f(unsigned short h) {
    union { unsigned int u; float f; } v; v.u = ((unsigned int)h) << 16;
    return v.f;
}
static __device__ __forceinline__ unsigned int pk2(float a, float b) {
    return (unsigned int)f2bf(a) | ((unsigned int)f2bf(b) << 16);
}

// ---------------------------------------------------------------------------
// Kernel 0: prep W -> transposed split-bf16  WtS[col][k], col in [0,192).
// ---------------------------------------------------------------------------
__global__ __launch_bounds__(256) void prep_w(
    const float* __restrict__ wq, const float* __restrict__ wk,
    const float* __restrict__ wv,
    u16* __restrict__ WtSh, u16* __restrict__ WtSl)
{
    int tid = blockIdx.x * 256 + threadIdx.x;   // 0..24575
    int col = tid >> 7;                          // 0..191
    int ch  = tid & 127;                         // k-chunk of 8
    const float* W = (col < 64) ? wq : (col < 128) ? wk : wv;
    int wcol = col & 63;
    int k0 = ch * 8;
    U8 H, L;
#pragma unroll
    for (int i = 0; i < 8; ++i) {
        float x = W[(size_t)(k0 + i) * DH + wcol];
        H.h[i] = f2bf(x);
        L.h[i] = f2bf(x - bf2f(H.h[i]));
    }
    *(uint4*)&WtSh[(size_t)col * EMB + k0] = H.u;
    *(uint4*)&WtSl[(size_t)col * EMB + k0] = L.u;
}

// ---------------------------------------------------------------------------
// Kernel 1: MFMA projection, split-bf16, K-split partials.
// grid (32 rowblocks, 2 colblocks, KSPLIT). 256 thr = 4 waves.
// Block: 128 rows x 96 cols, K-range 256 (4 steps of BK=64).
// Wave w: rows [w*32, w*32+32) x all 96 cols (3 col-tiles of 32).
// ---------------------------------------------------------------------------
__global__ __launch_bounds__(256) void proj_mfma(
    const float* __restrict__ tokens,
    const u16* __restrict__ WtSh, const u16* __restrict__ WtSl,
    float* __restrict__ part)
{
    __shared__ u16 Th[128][64];   // 16 KB, swizzled slots
    __shared__ u16 Tl[128][64];   // 16 KB
    __shared__ u16 Wh[96][64];    // 12 KB
    __shared__ u16 Wl[96][64];    // 12 KB

    const int t  = threadIdx.x;
    const int rb = blockIdx.x;
    const int cb = blockIdx.y;
    const int ks = blockIdx.z;
    const int w    = t >> 6;
    const int lane = t & 63;
    const int g    = lane >> 5;
    const int c    = lane & 31;
    const int rowbase = rb * 128;

    f32x16 acc[3];
#pragma unroll
    for (int ct = 0; ct < 3; ++ct)
#pragma unroll
        for (int i = 0; i < 16; ++i) acc[ct][i] = 0.f;

    for (int st = 0; st < 4; ++st) {
        const int kbase = ks * (EMB / KSPLIT) + st * 64;
        __syncthreads();
        // ---- stage tokens: 128 rows x 64 k, f32 -> split bf16, swizzled ----
#pragma unroll
        for (int i = 0; i < 4; ++i) {
            int idx = t + 256 * i;          // 0..1023
            int r = idx >> 3;               // 0..127
            int slot = idx & 7;             // 8-elem k-group
            const float* gp = tokens + (size_t)(rowbase + r) * EMB + kbase + slot * 8;
            float4 a = *(const float4*)gp;
            float4 b = *(const float4*)(gp + 4);
            float x[8] = {a.x, a.y, a.z, a.w, b.x, b.y, b.z, b.w};
            U8 H, L;
#pragma unroll
            for (int j = 0; j < 8; ++j) {
                H.h[j] = f2bf(x[j]);
                L.h[j] = f2bf(x[j] - bf2f(H.h[j]));
            }
            int dst = (slot ^ (r & 7)) * 8;
            *(uint4*)&Th[r][dst] = H.u;
            *(uint4*)&Tl[r][dst] = L.u;
        }
        // ---- stage W: 96 cols x 64 k from pre-split global, swizzled ----
#pragma unroll
        for (int i = 0; i < 3; ++i) {
            int idx = t + 256 * i;          // 0..767
            int r = idx >> 3;               // 0..95
            int slot = idx & 7;
            size_t gidx = (size_t)(cb * 96 + r) * EMB + kbase + slot * 8;
            uint4 h = *(const uint4*)&WtSh[gidx];
            uint4 l = *(const uint4*)&WtSl[gidx];
            int dst = (slot ^ (r & 7)) * 8;
            *(uint4*)&Wh[r][dst] = h;
            *(uint4*)&Wl[r][dst] = l;
        }
        __syncthreads();

        // ---- MFMA: 4 kt-substeps of k=16; 3 split passes per col-tile ----
#pragma unroll
        for (int kt = 0; kt < 4; ++kt) {
            int sA = kt * 2 + g;
            int offA = ((sA ^ (c & 7)) * 8);
            short8 ah = *(const short8*)&Th[w * 32 + c][offA];
            short8 al = *(const short8*)&Tl[w * 32 + c][offA];
#pragma unroll
            for (int ct = 0; ct < 3; ++ct) {
                short8 bh = *(const short8*)&Wh[ct * 32 + c][offA];
                short8 bl = *(const short8*)&Wl[ct * 32 + c][offA];
                acc[ct] = __builtin_amdgcn_mfma_f32_32x32x16_bf16(ah, bh, acc[ct], 0, 0, 0);
                acc[ct] = __builtin_amdgcn_mfma_f32_32x32x16_bf16(ah, bl, acc[ct], 0, 0, 0);
                acc[ct] = __builtin_amdgcn_mfma_f32_32x32x16_bf16(al, bh, acc[ct], 0, 0, 0);
            }
        }
    }

    // ---- epilogue: partial f32 ----
#pragma unroll
    for (int ct = 0; ct < 3; ++ct)
#pragma unroll
        for (int r = 0; r < 16; ++r) {
            int row_l = (r & 3) + 8 * (r >> 2) + 4 * g;
            part[((size_t)ks * NT + rowbase + w * 32 + row_l) * 192 + cb * 96 + ct * 32 + c]
                = acc[ct][r];
        }
}

// ---------------------------------------------------------------------------
// Kernel 2: merge KSPLIT partials + convert to attention input formats.
// Q -> split bf16 (Qhg/Qlg); K -> mask*0.125 folded, split bf16; V -> bf16.
// ---------------------------------------------------------------------------
__global__ __launch_bounds__(256) void merge_conv(
    const float* __restrict__ part, const float* __restrict__ mask,
    u16* __restrict__ Qhg, u16* __restrict__ Qlg,
    u16* __restrict__ Khg, u16* __restrict__ Klg, u16* __restrict__ Vbg)
{
    int tid = blockIdx.x * 256 + threadIdx.x;   // 0..98303
    int row = tid / 24;
    int c8  = tid % 24;
    int colbase = c8 * 8;

    float v[8];
#pragma unroll
    for (int i = 0; i < 8; ++i) v[i] = 0.f;
#pragma unroll
    for (int s = 0; s < KSPLIT; ++s) {
        const float* p = part + ((size_t)s * NT + row) * 192 + colbase;
        float4 a = *(const float4*)p;
        float4 b = *(const float4*)(p + 4);
        v[0] += a.x; v[1] += a.y; v[2] += a.z; v[3] += a.w;
        v[4] += b.x; v[5] += b.y; v[6] += b.z; v[7] += b.w;
    }

    int plane = colbase >> 6;      // 0=Q 1=K 2=V
    int pc = colbase & 63;
    size_t o = (size_t)row * DH + pc;
    if (plane == 0) {
        U8 H, L;
#pragma unroll
        for (int i = 0; i < 8; ++i) {
            H.h[i] = f2bf(v[i]);
            L.h[i] = f2bf(v[i] - bf2f(H.h[i]));
        }
        *(uint4*)&Qhg[o] = H.u;
        *(uint4*)&Qlg[o] = L.u;
    } else if (plane == 1) {
        float mk = mask[row] * 0.125f;
        U8 H, L;
#pragma unroll
        for (int i = 0; i < 8; ++i) {
            float x = v[i] * mk;
            H.h[i] = f2bf(x);
            L.h[i] = f2bf(x - bf2f(H.h[i]));
        }
        *(uint4*)&Khg[o] = H.u;
        *(uint4*)&Klg[o] = L.u;
    } else {
        U8 H;
#pragma unroll
        for (int i = 0; i < 8; ++i) H.h[i] = f2bf(v[i]);
        *(uint4*)&Vbg[o] = H.u;
    }
}

// ---------------------------------------------------------------------------
// Kernel 3: MFMA flash attention, split-bf16 logits (verified R2 structure).
// ---------------------------------------------------------------------------
__global__ __launch_bounds__(256) void attn_mfma(
    const u16* __restrict__ Qhg, const u16* __restrict__ Qlg,
    const u16* __restrict__ Khg, const u16* __restrict__ Klg,
    const u16* __restrict__ Vbg,
    float* __restrict__ opart, float* __restrict__ mlbuf)
{
    __shared__ u16 Kh[64][64];
    __shared__ u16 Kl[64][64];
    __shared__ unsigned int V2[32][64];

    const int t    = threadIdx.x;
    const int qb   = blockIdx.x;
    const int sp   = blockIdx.y;
    const int wq   = t >> 6;
    const int lane = t & 63;
    const int g    = lane >> 5;
    const int c    = lane & 31;
    const int qrow = qb * 128 + wq * 32 + c;

    // ---- Q fragments (pre-split) ----
    short8 qh[4], ql[4];
#pragma unroll
    for (int kt = 0; kt < 4; ++kt) {
        size_t o = (size_t)qrow * DH + kt * 16 + g * 8;
        U8 H, L;
        H.u = *(const uint4*)&Qhg[o];
        L.u = *(const uint4*)&Qlg[o];
        qh[kt] = H.s;
        ql[kt] = L.s;
    }

    f32x16 oa[2];
#pragma unroll
    for (int i = 0; i < 16; ++i) { oa[0][i] = 0.f; oa[1][i] = 0.f; }
    float m = -INFINITY, l = 0.f;

    for (int cb = 0; cb < KPS / KVB; ++cb) {
        const int kv = sp * KPS + cb * KVB;
        __syncthreads();
#pragma unroll
        for (int it = 0; it < 2; ++it) {
            int idx = it * 256 + t;
            int j = idx >> 3, gr = idx & 7;
            int colp = (gr * 8) ^ ((j & 7) * 8);
            *(uint4*)&Kh[j][colp] = *(const uint4*)&Khg[(size_t)(kv + j) * DH + gr * 8];
            *(uint4*)&Kl[j][colp] = *(const uint4*)&Klg[(size_t)(kv + j) * DH + gr * 8];
        }
        {
            int a2 = t >> 3, dg = t & 7;
            uint4 r0 = *(const uint4*)&Vbg[(size_t)(kv + a2 * 2) * DH + dg * 8];
            uint4 r1 = *(const uint4*)&Vbg[(size_t)(kv + a2 * 2 + 1) * DH + dg * 8];
            const unsigned int* p0 = (const unsigned int*)&r0;
            const unsigned int* p1 = (const unsigned int*)&r1;
            unsigned int wv_[8];
#pragma unroll
            for (int i = 0; i < 4; ++i) {
                wv_[2 * i]     = (p0[i] & 0xFFFFu) | (p1[i] << 16);
                wv_[2 * i + 1] = (p0[i] >> 16)     | (p1[i] & 0xFFFF0000u);
            }
            int colp = (dg * 8) ^ ((a2 & 7) * 8);
            *(uint4*)&V2[a2][colp]     = *(uint4*)&wv_[0];
            *(uint4*)&V2[a2][colp + 4] = *(uint4*)&wv_[4];
        }
        __syncthreads();

        f32x16 st0, st1;
#pragma unroll
        for (int i = 0; i < 16; ++i) { st0[i] = 0.f; st1[i] = 0.f; }
#pragma unroll
        for (int kt = 0; kt < 4; ++kt) {
            int colp = ((kt * 2 + g) * 8) ^ ((c & 7) * 8);
            short8 kh0 = *(const short8*)&Kh[c][colp];
            short8 kl0 = *(const short8*)&Kl[c][colp];
            short8 kh1 = *(const short8*)&Kh[32 + c][colp];
            short8 kl1 = *(const short8*)&Kl[32 + c][colp];
            st0 = __builtin_amdgcn_mfma_f32_32x32x16_bf16(kh0, qh[kt], st0, 0, 0, 0);
            st1 = __builtin_amdgcn_mfma_f32_32x32x16_bf16(kh1, qh[kt], st1, 0, 0, 0);
            st0 = __builtin_amdgcn_mfma_f32_32x32x16_bf16(kh0, ql[kt], st0, 0, 0, 0);
            st1 = __builtin_amdgcn_mfma_f32_32x32x16_bf16(kh1, ql[kt], st1, 0, 0, 0);
            st0 = __builtin_amdgcn_mfma_f32_32x32x16_bf16(kl0, qh[kt], st0, 0, 0, 0);
            st1 = __builtin_amdgcn_mfma_f32_32x32x16_bf16(kl1, qh[kt], st1, 0, 0, 0);
        }

        float p[32];
        float pm = -INFINITY;
#pragma unroll
        for (int r = 0; r < 16; ++r) {
            pm = fmaxf(pm, st0[r]);
            pm = fmaxf(pm, st1[r]);
        }
        pm = fmaxf(pm, __shfl_xor(pm, 32));
        float mn = fmaxf(m, pm);
        float f  = __expf(m - mn);
        float rs = 0.f;
#pragma unroll
        for (int r = 0; r < 16; ++r) { p[r]      = __expf(st0[r] - mn); rs += p[r]; }
#pragma unroll
        for (int r = 0; r < 16; ++r) { p[16 + r] = __expf(st1[r] - mn); rs += p[16 + r]; }
        rs += __shfl_xor(rs, 32);
        l = l * f + rs;
        m = mn;

        short8 pa[4];
#pragma unroll
        for (int jt = 0; jt < 2; ++jt) {
            const float* pp = &p[jt * 16];
            unsigned int A1 = pk2(pp[0], pp[1]),   B1 = pk2(pp[4], pp[5]);
            unsigned int A2 = pk2(pp[2], pp[3]),   B2 = pk2(pp[6], pp[7]);
            unsigned int A3 = pk2(pp[8], pp[9]),   B3 = pk2(pp[12], pp[13]);
            unsigned int A4 = pk2(pp[10], pp[11]), B4 = pk2(pp[14], pp[15]);
            unsigned int xA1 = (unsigned int)__shfl_xor((int)A1, 32);
            unsigned int xB1 = (unsigned int)__shfl_xor((int)B1, 32);
            unsigned int xA2 = (unsigned int)__shfl_xor((int)A2, 32);
            unsigned int xB2 = (unsigned int)__shfl_xor((int)B2, 32);
            unsigned int xA3 = (unsigned int)__shfl_xor((int)A3, 32);
            unsigned int xB3 = (unsigned int)__shfl_xor((int)B3, 32);
            unsigned int xA4 = (unsigned int)__shfl_xor((int)A4, 32);
            unsigned int xB4 = (unsigned int)__shfl_xor((int)B4, 32);
            U8 f0, f1;
            f0.w[0] = g ? xB1 : A1;
            f0.w[1] = g ? xB2 : A2;
            f0.w[2] = g ? B1  : xA1;
            f0.w[3] = g ? B2  : xA2;
            f1.w[0] = g ? xB3 : A3;
            f1.w[1] = g ? xB4 : A4;
            f1.w[2] = g ? B3  : xA3;
            f1.w[3] = g ? B4  : xA4;
            pa[jt * 2]     = f0.s;
            pa[jt * 2 + 1] = f1.s;
        }

#pragma unroll
        for (int r = 0; r < 16; ++r) {
            float fr = __shfl(f, (r & 3) + 8 * (r >> 2) + 4 * g);
            oa[0][r] *= fr;
            oa[1][r] *= fr;
        }

#pragma unroll
        for (int dt = 0; dt < 2; ++dt) {
#pragma unroll
            for (int ksl = 0; ksl < 4; ++ksl) {
                U8 bf;
#pragma unroll
                for (int pq = 0; pq < 4; ++pq) {
                    int j2 = ksl * 8 + g * 4 + pq;
                    int col = (dt * 32 + c) ^ ((j2 & 7) * 8);
                    bf.w[pq] = V2[j2][col];
                }
                oa[dt] = __builtin_amdgcn_mfma_f32_32x32x16_bf16(pa[ksl], bf.s, oa[dt], 0, 0, 0);
            }
        }
    }

#pragma unroll
    for (int dt = 0; dt < 2; ++dt)
#pragma unroll
        for (int r = 0; r < 16; ++r) {
            int row = qb * 128 + wq * 32 + ((r & 3) + 8 * (r >> 2) + 4 * g);
            opart[((size_t)sp * NT + row) * DH + dt * 32 + c] = oa[dt][r];
        }
    if (lane < 32) {
        int row = qb * 128 + wq * 32 + lane;
        mlbuf[((size_t)sp * NT + row) * 2 + 0] = m;
        mlbuf[((size_t)sp * NT + row) * 2 + 1] = l;
    }
}

// ---------------------------------------------------------------------------
// Kernel 4: merge NSPLIT attention partials -> final output.
// ---------------------------------------------------------------------------
__global__ __launch_bounds__(256) void merge_kernel(
    const float* __restrict__ opart, const float* __restrict__ mlbuf,
    float* __restrict__ out)
{
    int idx = (blockIdx.x * 256 + threadIdx.x) * 4;
    int row = idx >> 6;
    int d0  = idx & 63;

    float mv[NSPLIT], lv[NSPLIT];
    float mstar = -INFINITY;
#pragma unroll
    for (int s = 0; s < NSPLIT; ++s) {
        mv[s] = mlbuf[((size_t)s * NT + row) * 2 + 0];
        lv[s] = mlbuf[((size_t)s * NT + row) * 2 + 1];
        mstar = fmaxf(mstar, mv[s]);
    }
    float denom = 0.f;
    float ax = 0.f, ay = 0.f, az = 0.f, aw = 0.f;
#pragma unroll
    for (int s = 0; s < NSPLIT; ++s) {
        float w = __expf(mv[s] - mstar);
        denom += w * lv[s];
        float4 ov = *(const float4*)&opart[((size_t)s * NT + row) * DH + d0];
        ax += w * ov.x; ay += w * ov.y; az += w * ov.z; aw += w * ov.w;
    }
    float inv = 1.f / denom;
    *(float4*)&out[idx] = make_float4(ax * inv, ay * inv, az * inv, aw * inv);
}

// ---------------------------------------------------------------------------
extern "C" void kernel_launch(void* const* d_in, const int* in_sizes, int n_in,
                              void* d_out, int out_size, void* d_ws, size_t ws_size,
                              hipStream_t stream) {
    const float* tokens = (const float*)d_in[0];
    const float* mask   = (const float*)d_in[1];
    const float* wq     = (const float*)d_in[2];
    const float* wk     = (const float*)d_in[3];
    const float* wv     = (const float*)d_in[4];

    char* wsb = (char*)d_ws;
    u16* WtSh = (u16*)wsb;                          // 192*1024*2 = 384 KB
    u16* WtSl = WtSh + 192 * EMB;                   // 384 KB
    u16* Qhg  = WtSl + 192 * EMB;
    u16* Qlg  = Qhg + PLANE;
    u16* Khg  = Qlg + PLANE;
    u16* Klg  = Khg + PLANE;
    u16* Vbg  = Klg + PLANE;                        // 5 x 512 KB
    float* window = (float*)(Vbg + PLANE);
    float* part   = window;                          // KSPLIT*4096*192 f32 = 12 MB
    float* opart  = window;                          // reused after merge_conv
    float* mlbuf  = window + (size_t)NSPLIT * PLANE; // 8 MB offset, 256 KB
    float* out    = (float*)d_out;

    hipLaunchKernelGGL(prep_w, dim3(96), dim3(256), 0, stream,
                       wq, wk, wv, WtSh, WtSl);
    hipLaunchKernelGGL(proj_mfma, dim3(32, 2, KSPLIT), dim3(256), 0, stream,
                       tokens, WtSh, WtSl, part);
    hipLaunchKernelGGL(merge_conv, dim3(384), dim3(256), 0, stream,
                       part, mask, Qhg, Qlg, Khg, Klg, Vbg);
    hipLaunchKernelGGL(attn_mfma, dim3(NT / 128, NSPLIT), dim3(256), 0, stream,
                       Qhg, Qlg, Khg, Klg, Vbg, opart, mlbuf);
    hipLaunchKernelGGL(merge_kernel, dim3(256), dim3(256), 0, stream,
                       opart, mlbuf, out);
}

// Round 4
// 53.830 us; speedup vs baseline: 2.7825x; 1.0431x over previous
//
#include <hip/hip_runtime.h>
#include <math.h>

#define NT 4096
#define EMB 1024
#define DH 64
#define PLANE (NT * DH)          // 262144
#define NSPLIT 16                // attention K-split (2 blocks/CU)
#define KPS (NT / NSPLIT)        // 256
#define KVB 64
#define KSPLIT 8                 // projection K-split (EMB/8 = 128 per block)

typedef __attribute__((ext_vector_type(8))) short short8;
typedef __attribute__((ext_vector_type(16))) float f32x16;
typedef unsigned short u16;

union U8 { short8 s; uint4 u; unsigned short h[8]; unsigned int w[4]; };

static __device__ __forceinline__ unsigned short f2bf(float x) {
    union { float f; unsigned int u; } v; v.f = x;
    unsigned int r = v.u + 0x7fffu + ((v.u >> 16) & 1u);
    return (unsigned short)(r >> 16);
}
static __device__ __forceinline__ float bf2f(unsigned short h) {
    union { unsigned int u; float f; } v; v.u = ((unsigned int)h) << 16;
    return v.f;
}
static __device__ __forceinline__ unsigned int pk2(float a, float b) {
    return (unsigned int)f2bf(a) | ((unsigned int)f2bf(b) << 16);
}

// ---------------------------------------------------------------------------
// Kernel 0: prep W -> transposed split-bf16  WtS[col][k], col in [0,192).
// ---------------------------------------------------------------------------
__global__ __launch_bounds__(256) void prep_w(
    const float* __restrict__ wq, const float* __restrict__ wk,
    const float* __restrict__ wv,
    u16* __restrict__ WtSh, u16* __restrict__ WtSl)
{
    int tid = blockIdx.x * 256 + threadIdx.x;   // 0..24575
    int col = tid >> 7;                          // 0..191
    int ch  = tid & 127;                         // k-chunk of 8
    const float* W = (col < 64) ? wq : (col < 128) ? wk : wv;
    int wcol = col & 63;
    int k0 = ch * 8;
    U8 H, L;
#pragma unroll
    for (int i = 0; i < 8; ++i) {
        float x = W[(size_t)(k0 + i) * DH + wcol];
        H.h[i] = f2bf(x);
        L.h[i] = f2bf(x - bf2f(H.h[i]));
    }
    *(uint4*)&WtSh[(size_t)col * EMB + k0] = H.u;
    *(uint4*)&WtSl[(size_t)col * EMB + k0] = L.u;
}

// ---------------------------------------------------------------------------
// Kernel 1: MFMA projection, split-bf16, K-split partials.
// grid (32 rowblocks, 2 colblocks, KSPLIT=8) = 512 blocks (2/CU). 4 waves.
// Block: 128 rows x 96 cols, K-range 128 (2 steps of BK=64).
// ---------------------------------------------------------------------------
__global__ __launch_bounds__(256) void proj_mfma(
    const float* __restrict__ tokens,
    const u16* __restrict__ WtSh, const u16* __restrict__ WtSl,
    float* __restrict__ part)
{
    __shared__ u16 Th[128][64];   // 16 KB, swizzled slots
    __shared__ u16 Tl[128][64];   // 16 KB
    __shared__ u16 Wh[96][64];    // 12 KB
    __shared__ u16 Wl[96][64];    // 12 KB

    const int t  = threadIdx.x;
    const int rb = blockIdx.x;
    const int cb = blockIdx.y;
    const int ks = blockIdx.z;
    const int w    = t >> 6;
    const int lane = t & 63;
    const int g    = lane >> 5;
    const int c    = lane & 31;
    const int rowbase = rb * 128;

    f32x16 acc[3];
#pragma unroll
    for (int ct = 0; ct < 3; ++ct)
#pragma unroll
        for (int i = 0; i < 16; ++i) acc[ct][i] = 0.f;

    for (int st = 0; st < 2; ++st) {
        const int kbase = ks * (EMB / KSPLIT) + st * 64;
        __syncthreads();
        // ---- stage tokens: 128 rows x 64 k, f32 -> split bf16, swizzled ----
#pragma unroll
        for (int i = 0; i < 4; ++i) {
            int idx = t + 256 * i;          // 0..1023
            int r = idx >> 3;               // 0..127
            int slot = idx & 7;             // 8-elem k-group
            const float* gp = tokens + (size_t)(rowbase + r) * EMB + kbase + slot * 8;
            float4 a = *(const float4*)gp;
            float4 b = *(const float4*)(gp + 4);
            float x[8] = {a.x, a.y, a.z, a.w, b.x, b.y, b.z, b.w};
            U8 H, L;
#pragma unroll
            for (int j = 0; j < 8; ++j) {
                H.h[j] = f2bf(x[j]);
                L.h[j] = f2bf(x[j] - bf2f(H.h[j]));
            }
            int dst = (slot ^ (r & 7)) * 8;
            *(uint4*)&Th[r][dst] = H.u;
            *(uint4*)&Tl[r][dst] = L.u;
        }
        // ---- stage W: 96 cols x 64 k from pre-split global, swizzled ----
#pragma unroll
        for (int i = 0; i < 3; ++i) {
            int idx = t + 256 * i;          // 0..767
            int r = idx >> 3;               // 0..95
            int slot = idx & 7;
            size_t gidx = (size_t)(cb * 96 + r) * EMB + kbase + slot * 8;
            uint4 h = *(const uint4*)&WtSh[gidx];
            uint4 l = *(const uint4*)&WtSl[gidx];
            int dst = (slot ^ (r & 7)) * 8;
            *(uint4*)&Wh[r][dst] = h;
            *(uint4*)&Wl[r][dst] = l;
        }
        __syncthreads();

        // ---- MFMA: 4 kt-substeps of k=16; 3 split passes per col-tile ----
#pragma unroll
        for (int kt = 0; kt < 4; ++kt) {
            int sA = kt * 2 + g;
            int offA = ((sA ^ (c & 7)) * 8);
            short8 ah = *(const short8*)&Th[w * 32 + c][offA];
            short8 al = *(const short8*)&Tl[w * 32 + c][offA];
#pragma unroll
            for (int ct = 0; ct < 3; ++ct) {
                short8 bh = *(const short8*)&Wh[ct * 32 + c][offA];
                short8 bl = *(const short8*)&Wl[ct * 32 + c][offA];
                acc[ct] = __builtin_amdgcn_mfma_f32_32x32x16_bf16(ah, bh, acc[ct], 0, 0, 0);
                acc[ct] = __builtin_amdgcn_mfma_f32_32x32x16_bf16(ah, bl, acc[ct], 0, 0, 0);
                acc[ct] = __builtin_amdgcn_mfma_f32_32x32x16_bf16(al, bh, acc[ct], 0, 0, 0);
            }
        }
    }

    // ---- epilogue: partial f32 ----
#pragma unroll
    for (int ct = 0; ct < 3; ++ct)
#pragma unroll
        for (int r = 0; r < 16; ++r) {
            int row_l = (r & 3) + 8 * (r >> 2) + 4 * g;
            part[((size_t)ks * NT + rowbase + w * 32 + row_l) * 192 + cb * 96 + ct * 32 + c]
                = acc[ct][r];
        }
}

// ---------------------------------------------------------------------------
// Kernel 2: merge KSPLIT partials + convert to attention input formats.
// ---------------------------------------------------------------------------
__global__ __launch_bounds__(256) void merge_conv(
    const float* __restrict__ part, const float* __restrict__ mask,
    u16* __restrict__ Qhg, u16* __restrict__ Qlg,
    u16* __restrict__ Khg, u16* __restrict__ Klg, u16* __restrict__ Vbg)
{
    int tid = blockIdx.x * 256 + threadIdx.x;   // 0..98303
    int row = tid / 24;
    int c8  = tid % 24;
    int colbase = c8 * 8;

    float v[8];
#pragma unroll
    for (int i = 0; i < 8; ++i) v[i] = 0.f;
#pragma unroll
    for (int s = 0; s < KSPLIT; ++s) {
        const float* p = part + ((size_t)s * NT + row) * 192 + colbase;
        float4 a = *(const float4*)p;
        float4 b = *(const float4*)(p + 4);
        v[0] += a.x; v[1] += a.y; v[2] += a.z; v[3] += a.w;
        v[4] += b.x; v[5] += b.y; v[6] += b.z; v[7] += b.w;
    }

    int plane = colbase >> 6;      // 0=Q 1=K 2=V
    int pc = colbase & 63;
    size_t o = (size_t)row * DH + pc;
    if (plane == 0) {
        U8 H, L;
#pragma unroll
        for (int i = 0; i < 8; ++i) {
            H.h[i] = f2bf(v[i]);
            L.h[i] = f2bf(v[i] - bf2f(H.h[i]));
        }
        *(uint4*)&Qhg[o] = H.u;
        *(uint4*)&Qlg[o] = L.u;
    } else if (plane == 1) {
        float mk = mask[row] * 0.125f;
        U8 H, L;
#pragma unroll
        for (int i = 0; i < 8; ++i) {
            float x = v[i] * mk;
            H.h[i] = f2bf(x);
            L.h[i] = f2bf(x - bf2f(H.h[i]));
        }
        *(uint4*)&Khg[o] = H.u;
        *(uint4*)&Klg[o] = L.u;
    } else {
        U8 H;
#pragma unroll
        for (int i = 0; i < 8; ++i) H.h[i] = f2bf(v[i]);
        *(uint4*)&Vbg[o] = H.u;
    }
}

// ---------------------------------------------------------------------------
// Kernel 3: MFMA flash attention, split-bf16 logits.
// grid (32, NSPLIT=16) = 512 blocks (2/CU). 4 waves x 32 q = 128 q/block.
// ---------------------------------------------------------------------------
__global__ __launch_bounds__(256) void attn_mfma(
    const u16* __restrict__ Qhg, const u16* __restrict__ Qlg,
    const u16* __restrict__ Khg, const u16* __restrict__ Klg,
    const u16* __restrict__ Vbg,
    float* __restrict__ opart, float* __restrict__ mlbuf)
{
    __shared__ u16 Kh[64][64];
    __shared__ u16 Kl[64][64];
    __shared__ unsigned int V2[32][64];

    const int t    = threadIdx.x;
    const int qb   = blockIdx.x;
    const int sp   = blockIdx.y;
    const int wq   = t >> 6;
    const int lane = t & 63;
    const int g    = lane >> 5;
    const int c    = lane & 31;
    const int qrow = qb * 128 + wq * 32 + c;

    // ---- Q fragments (pre-split) ----
    short8 qh[4], ql[4];
#pragma unroll
    for (int kt = 0; kt < 4; ++kt) {
        size_t o = (size_t)qrow * DH + kt * 16 + g * 8;
        U8 H, L;
        H.u = *(const uint4*)&Qhg[o];
        L.u = *(const uint4*)&Qlg[o];
        qh[kt] = H.s;
        ql[kt] = L.s;
    }

    f32x16 oa[2];
#pragma unroll
    for (int i = 0; i < 16; ++i) { oa[0][i] = 0.f; oa[1][i] = 0.f; }
    float m = -INFINITY, l = 0.f;

    for (int cb = 0; cb < KPS / KVB; ++cb) {
        const int kv = sp * KPS + cb * KVB;
        __syncthreads();
#pragma unroll
        for (int it = 0; it < 2; ++it) {
            int idx = it * 256 + t;
            int j = idx >> 3, gr = idx & 7;
            int colp = (gr * 8) ^ ((j & 7) * 8);
            *(uint4*)&Kh[j][colp] = *(const uint4*)&Khg[(size_t)(kv + j) * DH + gr * 8];
            *(uint4*)&Kl[j][colp] = *(const uint4*)&Klg[(size_t)(kv + j) * DH + gr * 8];
        }
        {
            int a2 = t >> 3, dg = t & 7;
            uint4 r0 = *(const uint4*)&Vbg[(size_t)(kv + a2 * 2) * DH + dg * 8];
            uint4 r1 = *(const uint4*)&Vbg[(size_t)(kv + a2 * 2 + 1) * DH + dg * 8];
            const unsigned int* p0 = (const unsigned int*)&r0;
            const unsigned int* p1 = (const unsigned int*)&r1;
            unsigned int wv_[8];
#pragma unroll
            for (int i = 0; i < 4; ++i) {
                wv_[2 * i]     = (p0[i] & 0xFFFFu) | (p1[i] << 16);
                wv_[2 * i + 1] = (p0[i] >> 16)     | (p1[i] & 0xFFFF0000u);
            }
            int colp = (dg * 8) ^ ((a2 & 7) * 8);
            *(uint4*)&V2[a2][colp]     = *(uint4*)&wv_[0];
            *(uint4*)&V2[a2][colp + 4] = *(uint4*)&wv_[4];
        }
        __syncthreads();

        f32x16 st0, st1;
#pragma unroll
        for (int i = 0; i < 16; ++i) { st0[i] = 0.f; st1[i] = 0.f; }
#pragma unroll
        for (int kt = 0; kt < 4; ++kt) {
            int colp = ((kt * 2 + g) * 8) ^ ((c & 7) * 8);
            short8 kh0 = *(const short8*)&Kh[c][colp];
            short8 kl0 = *(const short8*)&Kl[c][colp];
            short8 kh1 = *(const short8*)&Kh[32 + c][colp];
            short8 kl1 = *(const short8*)&Kl[32 + c][colp];
            st0 = __builtin_amdgcn_mfma_f32_32x32x16_bf16(kh0, qh[kt], st0, 0, 0, 0);
            st1 = __builtin_amdgcn_mfma_f32_32x32x16_bf16(kh1, qh[kt], st1, 0, 0, 0);
            st0 = __builtin_amdgcn_mfma_f32_32x32x16_bf16(kh0, ql[kt], st0, 0, 0, 0);
            st1 = __builtin_amdgcn_mfma_f32_32x32x16_bf16(kh1, ql[kt], st1, 0, 0, 0);
            st0 = __builtin_amdgcn_mfma_f32_32x32x16_bf16(kl0, qh[kt], st0, 0, 0, 0);
            st1 = __builtin_amdgcn_mfma_f32_32x32x16_bf16(kl1, qh[kt], st1, 0, 0, 0);
        }

        float p[32];
        float pm = -INFINITY;
#pragma unroll
        for (int r = 0; r < 16; ++r) {
            pm = fmaxf(pm, st0[r]);
            pm = fmaxf(pm, st1[r]);
        }
        pm = fmaxf(pm, __shfl_xor(pm, 32));
        float mn = fmaxf(m, pm);
        float f  = __expf(m - mn);
        float rs = 0.f;
#pragma unroll
        for (int r = 0; r < 16; ++r) { p[r]      = __expf(st0[r] - mn); rs += p[r]; }
#pragma unroll
        for (int r = 0; r < 16; ++r) { p[16 + r] = __expf(st1[r] - mn); rs += p[16 + r]; }
        rs += __shfl_xor(rs, 32);
        l = l * f + rs;
        m = mn;

        short8 pa[4];
#pragma unroll
        for (int jt = 0; jt < 2; ++jt) {
            const float* pp = &p[jt * 16];
            unsigned int A1 = pk2(pp[0], pp[1]),   B1 = pk2(pp[4], pp[5]);
            unsigned int A2 = pk2(pp[2], pp[3]),   B2 = pk2(pp[6], pp[7]);
            unsigned int A3 = pk2(pp[8], pp[9]),   B3 = pk2(pp[12], pp[13]);
            unsigned int A4 = pk2(pp[10], pp[11]), B4 = pk2(pp[14], pp[15]);
            unsigned int xA1 = (unsigned int)__shfl_xor((int)A1, 32);
            unsigned int xB1 = (unsigned int)__shfl_xor((int)B1, 32);
            unsigned int xA2 = (unsigned int)__shfl_xor((int)A2, 32);
            unsigned int xB2 = (unsigned int)__shfl_xor((int)B2, 32);
            unsigned int xA3 = (unsigned int)__shfl_xor((int)A3, 32);
            unsigned int xB3 = (unsigned int)__shfl_xor((int)B3, 32);
            unsigned int xA4 = (unsigned int)__shfl_xor((int)A4, 32);
            unsigned int xB4 = (unsigned int)__shfl_xor((int)B4, 32);
            U8 f0, f1;
            f0.w[0] = g ? xB1 : A1;
            f0.w[1] = g ? xB2 : A2;
            f0.w[2] = g ? B1  : xA1;
            f0.w[3] = g ? B2  : xA2;
            f1.w[0] = g ? xB3 : A3;
            f1.w[1] = g ? xB4 : A4;
            f1.w[2] = g ? B3  : xA3;
            f1.w[3] = g ? B4  : xA4;
            pa[jt * 2]     = f0.s;
            pa[jt * 2 + 1] = f1.s;
        }

#pragma unroll
        for (int r = 0; r < 16; ++r) {
            float fr = __shfl(f, (r & 3) + 8 * (r >> 2) + 4 * g);
            oa[0][r] *= fr;
            oa[1][r] *= fr;
        }

#pragma unroll
        for (int dt = 0; dt < 2; ++dt) {
#pragma unroll
            for (int ksl = 0; ksl < 4; ++ksl) {
                U8 bf;
#pragma unroll
                for (int pq = 0; pq < 4; ++pq) {
                    int j2 = ksl * 8 + g * 4 + pq;
                    int col = (dt * 32 + c) ^ ((j2 & 7) * 8);
                    bf.w[pq] = V2[j2][col];
                }
                oa[dt] = __builtin_amdgcn_mfma_f32_32x32x16_bf16(pa[ksl], bf.s, oa[dt], 0, 0, 0);
            }
        }
    }

#pragma unroll
    for (int dt = 0; dt < 2; ++dt)
#pragma unroll
        for (int r = 0; r < 16; ++r) {
            int row = qb * 128 + wq * 32 + ((r & 3) + 8 * (r >> 2) + 4 * g);
            opart[((size_t)sp * NT + row) * DH + dt * 32 + c] = oa[dt][r];
        }
    if (lane < 32) {
        int row = qb * 128 + wq * 32 + lane;
        mlbuf[((size_t)sp * NT + row) * 2 + 0] = m;
        mlbuf[((size_t)sp * NT + row) * 2 + 1] = l;
    }
}

// ---------------------------------------------------------------------------
// Kernel 4: merge NSPLIT attention partials -> final output.
// ---------------------------------------------------------------------------
__global__ __launch_bounds__(256) void merge_kernel(
    const float* __restrict__ opart, const float* __restrict__ mlbuf,
    float* __restrict__ out)
{
    int idx = (blockIdx.x * 256 + threadIdx.x) * 4;
    int row = idx >> 6;
    int d0  = idx & 63;

    float mv[NSPLIT], lv[NSPLIT];
    float mstar = -INFINITY;
#pragma unroll
    for (int s = 0; s < NSPLIT; ++s) {
        mv[s] = mlbuf[((size_t)s * NT + row) * 2 + 0];
        lv[s] = mlbuf[((size_t)s * NT + row) * 2 + 1];
        mstar = fmaxf(mstar, mv[s]);
    }
    float denom = 0.f;
    float ax = 0.f, ay = 0.f, az = 0.f, aw = 0.f;
#pragma unroll
    for (int s = 0; s < NSPLIT; ++s) {
        float w = __expf(mv[s] - mstar);
        denom += w * lv[s];
        float4 ov = *(const float4*)&opart[((size_t)s * NT + row) * DH + d0];
        ax += w * ov.x; ay += w * ov.y; az += w * ov.z; aw += w * ov.w;
    }
    float inv = 1.f / denom;
    *(float4*)&out[idx] = make_float4(ax * inv, ay * inv, az * inv, aw * inv);
}

// ---------------------------------------------------------------------------
extern "C" void kernel_launch(void* const* d_in, const int* in_sizes, int n_in,
                              void* d_out, int out_size, void* d_ws, size_t ws_size,
                              hipStream_t stream) {
    const float* tokens = (const float*)d_in[0];
    const float* mask   = (const float*)d_in[1];
    const float* wq     = (const float*)d_in[2];
    const float* wk     = (const float*)d_in[3];
    const float* wv     = (const float*)d_in[4];

    char* wsb = (char*)d_ws;
    u16* WtSh = (u16*)wsb;                          // 384 KB
    u16* WtSl = WtSh + 192 * EMB;                   // 384 KB
    u16* Qhg  = WtSl + 192 * EMB;
    u16* Qlg  = Qhg + PLANE;
    u16* Khg  = Qlg + PLANE;
    u16* Klg  = Khg + PLANE;
    u16* Vbg  = Klg + PLANE;                        // 5 x 512 KB
    float* window = (float*)(Vbg + PLANE);
    float* part   = window;                          // KSPLIT*4096*192 f32 = 24 MB
    float* opart  = window;                          // reused after merge_conv (16 MB)
    float* mlbuf  = window + (size_t)NSPLIT * PLANE; // 512 KB after opart
    float* out    = (float*)d_out;

    hipLaunchKernelGGL(prep_w, dim3(96), dim3(256), 0, stream,
                       wq, wk, wv, WtSh, WtSl);
    hipLaunchKernelGGL(proj_mfma, dim3(32, 2, KSPLIT), dim3(256), 0, stream,
                       tokens, WtSh, WtSl, part);
    hipLaunchKernelGGL(merge_conv, dim3(384), dim3(256), 0, stream,
                       part, mask, Qhg, Qlg, Khg, Klg, Vbg);
    hipLaunchKernelGGL(attn_mfma, dim3(NT / 128, NSPLIT), dim3(256), 0, stream,
                       Qhg, Qlg, Khg, Klg, Vbg, opart, mlbuf);
    hipLaunchKernelGGL(merge_kernel, dim3(256), dim3(256), 0, stream,
                       opart, mlbuf, out);
}